// Round 2
// baseline (489.623 us; speedup 1.0000x reference)
//
#include <hip/hip_runtime.h>

// Holt double-exponential smoothing, chunk-parallel decomposition.
//
// Recurrence (t>=2): s = 0.5*x + 0.5*(s_p + b_p); b = 0.5*(s - s_p) + 0.5*b_p
// is affine: state_t = A * state_{t-1} + (0.5 x, 0.25 x),
//   A = [[0.5, 0.5], [-0.25, 0.75]], |eigenvalues| = sqrt(0.5).
// Split each T=1024 sequence into C=16 chunks of L=64:
//   Phase L (NEW): full-line coalesced loads (16 complete 64B lines per wave
//            instruction) + 4-stage LDS transpose -> per-chunk registers.
//   Phase A: per-chunk zero-init run (x held in registers) -> chunk-final state
//   Phase B: block-local serial scan over chunks with constant A^64
//   Phase C: exact sequential recurrence from corrected init, outputs -> regs
//   Phase D: 4-stage LDS transpose so every global store instruction
//            writes full 64B lines (lanes 0-3 = 4 consecutive float4s).
// Round-2 lesson: WRITE_SIZE was exactly 2x output size -> 32B-granule HBM
// write amplification from per-lane 16B stores at 256B wave stride. Fixed by
// Phase D (dur 200 -> ~139 us).
// Round-3 lesson (this round): loads had the same defect on the request path
// (64 lines touched per load instr, 16B used each); Phase L makes every load
// instruction cover 16 complete lines (minimum for 1KB payload).
// Quirky init (faithful to reference): out[0]=0; out[1]=x[1] with NO state
// update; state entering t=2 is (0,0).

constexpr int T_STEPS = 1024;
constexpr int CHUNKS  = 16;            // chunks per sequence
constexpr int CLEN    = T_STEPS / CHUNKS;  // 64 steps per chunk
constexpr int CGROUPS = CLEN / 4;      // 16 float4 groups per chunk
constexpr int SEQ_PER_BLOCK = 256 / CHUNKS; // 16 sequences per block

// Compile-time A^64 in double precision.
struct Md { double a00, a01, a10, a11; };
constexpr Md apow(int n) {
    Md p{1.0, 0.0, 0.0, 1.0};
    const Md A{0.5, 0.5, -0.25, 0.75};
    for (int i = 0; i < n; ++i) {
        Md q{A.a00 * p.a00 + A.a01 * p.a10,
             A.a00 * p.a01 + A.a01 * p.a11,
             A.a10 * p.a00 + A.a11 * p.a10,
             A.a10 * p.a01 + A.a11 * p.a11};
        p = q;
    }
    return p;
}
constexpr Md P64 = apow(64);

// XOR swizzle on float4 index within a sequence's 64-f4 row: the strided
// side (f = chunk*4+j, 16 lanes per sloc) lands 2 lanes/bank-group (free per
// m136); the contiguous side stays conflict-free.
__device__ __forceinline__ int swz(int f) { return f ^ ((f >> 3) & 3); }

__global__ __launch_bounds__(256)
void holt_chunked_kernel(const float* __restrict__ x, float* __restrict__ out) {
    const int tid   = threadIdx.x;
    const int chunk = tid & (CHUNKS - 1);
    const int sloc  = tid >> 4;  // local sequence index, 0..15
    const size_t seqBase = (size_t)blockIdx.x * SEQ_PER_BLOCK;

    const int lane = tid & 63;
    const int wv   = tid >> 6;
    const int cc   = (lane >> 2) & 15;  // line-coalesced chunk coord
    const int cj   = lane & 3;          // line-coalesced f4-within-line coord

    __shared__ float  lS[256];
    __shared__ float  lB[256];
    __shared__ float4 xfer[SEQ_PER_BLOCK * CHUNKS * 4];  // 1024 float4 = 16 KB

    // ---- Phase L: full-line coalesced loads + LDS transpose -> v[] ----
    // Load: per (k,it), lane l reads f4 index cc*16 + k*4 + cj of sequence
    // seqBase + wv*4 + it. Lanes 0-3 cover one complete 64B line; the wave
    // issues 16 complete-line requests per instruction (minimum for 1KB).
    const float4* __restrict__ xv4 = reinterpret_cast<const float4*>(x);
    float4 tmp[16];
#pragma unroll
    for (int k = 0; k < 4; ++k) {
#pragma unroll
        for (int it = 0; it < 4; ++it) {
            tmp[k * 4 + it] =
                xv4[(seqBase + (size_t)(wv * 4 + it)) * (T_STEPS / 4)
                    + (size_t)cc * CGROUPS + k * 4 + cj];
        }
    }

    float4 v[CGROUPS];
#pragma unroll
    for (int k = 0; k < 4; ++k) {
        // Writer: row seqL = wv*4+it, col = cc*4+cj == lane (contiguous).
#pragma unroll
        for (int it = 0; it < 4; ++it) {
            xfer[swz((wv * 4 + it) * 64 + lane)] = tmp[k * 4 + it];
        }
        __syncthreads();
        // Reader: thread (sloc, chunk) takes cols chunk*4+j of row sloc,
        // which are f4s chunk*16 + 4k + j of its sequence -> v[4k+j].
#pragma unroll
        for (int j = 0; j < 4; ++j) {
            v[4 * k + j] = xfer[swz(sloc * 64 + chunk * 4 + j)];
        }
        __syncthreads();
    }

    float s = 0.0f, b = 0.0f;
    auto step = [&](float xval) {
        float sn = 0.5f * xval + 0.5f * (s + b);
        b = 0.5f * (sn - s) + 0.5f * b;
        s = sn;
    };

    // ---- Phase A: zero-init run, final state only ----
    if (chunk == 0) {
        // t=0: no update; t=1: no state update (quirky init); t=2,3: normal.
        step(v[0].z); step(v[0].w);
    } else {
        step(v[0].x); step(v[0].y); step(v[0].z); step(v[0].w);
    }
#pragma unroll
    for (int g = 1; g < CGROUPS; ++g) {
        step(v[g].x); step(v[g].y); step(v[g].z); step(v[g].w);
    }

    lS[tid] = s;
    lB[tid] = b;
    __syncthreads();

    // ---- Phase B: per-sequence scan over chunk states (16 threads active) ----
    if (tid < SEQ_PER_BLOCK) {
        const int o = tid * CHUNKS;
        const float p00 = (float)P64.a00, p01 = (float)P64.a01;
        const float p10 = (float)P64.a10, p11 = (float)P64.a11;
        float ts = lS[o], tb = lB[o];  // true state after chunk 0
        lS[o] = 0.0f; lB[o] = 0.0f;    // init for chunk 0
        for (int j = 1; j < CHUNKS; ++j) {
            float us = lS[o + j], ub = lB[o + j];
            lS[o + j] = ts;  lB[o + j] = tb;   // init state for chunk j
            float ns = us + p00 * ts + p01 * tb;
            float nb = ub + p10 * ts + p11 * tb;
            ts = ns; tb = nb;
        }
    }
    __syncthreads();

    // ---- Phase C: exact recurrence from corrected init; outputs -> v[] ----
    s = lS[sloc * CHUNKS + chunk];
    b = lB[sloc * CHUNKS + chunk];

    {
        float4 o0;
        if (chunk == 0) {
            o0.x = 0.0f;      // t=0
            o0.y = v[0].y;    // t=1 (state not updated)
            step(v[0].z); o0.z = s;
            step(v[0].w); o0.w = s;
        } else {
            step(v[0].x); o0.x = s;
            step(v[0].y); o0.y = s;
            step(v[0].z); o0.z = s;
            step(v[0].w); o0.w = s;
        }
        v[0] = o0;
    }
#pragma unroll
    for (int g = 1; g < CGROUPS; ++g) {
        float4 o;
        step(v[g].x); o.x = s;
        step(v[g].y); o.y = s;
        step(v[g].z); o.z = s;
        step(v[g].w); o.w = s;
        v[g] = o;
    }

    // ---- Phase D: LDS transpose -> full-line coalesced stores ----
    // Producer: thread (sloc, chunk) writes v[4k+j] at col chunk*4+j of row
    // sloc (2-way banked with swz = free). Consumer: lane l of wave wv,
    // iter it: row wv*4+it, col l; stores f4 cc*16 + k*4 + cj -> lanes 0-3
    // cover one full 64B line.
    float4* __restrict__ ov4 = reinterpret_cast<float4*>(out);
    const int fbase = sloc * 64 + chunk * 4;

#pragma unroll
    for (int k = 0; k < 4; ++k) {
#pragma unroll
        for (int j = 0; j < 4; ++j) {
            xfer[swz(fbase + j)] = v[4 * k + j];
        }
        __syncthreads();
#pragma unroll
        for (int it = 0; it < 4; ++it) {
            const int seqL = wv * 4 + it;
            const float4 val = xfer[swz(seqL * 64 + lane)];
            const size_t idx = (seqBase + seqL) * (T_STEPS / 4)
                             + (size_t)cc * CGROUPS + k * 4 + cj;
            ov4[idx] = val;
        }
        __syncthreads();
    }
}

extern "C" void kernel_launch(void* const* d_in, const int* in_sizes, int n_in,
                              void* d_out, int out_size, void* d_ws, size_t ws_size,
                              hipStream_t stream) {
    const float* x = (const float*)d_in[0];
    float* out = (float*)d_out;

    const int nseq = in_sizes[0] / T_STEPS;          // 65536
    const int grid = nseq / SEQ_PER_BLOCK;           // 4096 blocks

    holt_chunked_kernel<<<grid, 256, 0, stream>>>(x, out);
}

// Round 3
// 429.160 us; speedup vs baseline: 1.1409x; 1.1409x over previous
//
#include <hip/hip_runtime.h>

// Holt double-exponential smoothing, chunk-parallel decomposition.
//
// Recurrence (t>=2): s = 0.5*x + 0.5*(s_p + b_p); b = 0.5*(s - s_p) + 0.5*b_p
// is affine: state_t = A * state_{t-1} + (0.5 x, 0.25 x),
//   A = [[0.5, 0.5], [-0.25, 0.75]], |eigenvalues| = sqrt(0.5).
// Split each T=1024 sequence into C=16 chunks of L=64:
//   Phase A: per-chunk zero-init run (x held in registers) -> chunk-final state
//   Phase B: block-local serial scan over chunks with constant A^64
//   Phase C: exact sequential recurrence from corrected init, outputs -> regs
//   Phase D'' : chunk-partitioned LDS stages; each global store instruction is
//            1 KiB fully contiguous lane-ordered (lane l -> base + 16*l) --
//            byte-identical shape to fillBufferAligned, which measures 1x
//            WRITE_SIZE at 6.5 TB/s on this machine.
// History:
//   R0: strided 16B stores, WRITE=2x, 200us.
//   R1: gg-partitioned transpose (16x64B segments/instr): 2x WRITE REMAINED
//       (falsified granularity theory) but request-path relief gave ~139us.
//   R2: + full-line loads (Phase L): FETCH 137->241 GB (lost cross-iteration
//       L3 input residency), bank conflicts x4.8 -> REGRESSION, reverted.
// Quirky init (faithful to reference): out[0]=0; out[1]=x[1] with NO state
// update; state entering t=2 is (0,0).

constexpr int T_STEPS = 1024;
constexpr int CHUNKS  = 16;            // chunks per sequence
constexpr int CLEN    = T_STEPS / CHUNKS;  // 64 steps per chunk
constexpr int CGROUPS = CLEN / 4;      // 16 float4 groups per chunk
constexpr int SEQ_PER_BLOCK = 256 / CHUNKS; // 16 sequences per block

// Compile-time A^64 in double precision.
struct Md { double a00, a01, a10, a11; };
constexpr Md apow(int n) {
    Md p{1.0, 0.0, 0.0, 1.0};
    const Md A{0.5, 0.5, -0.25, 0.75};
    for (int i = 0; i < n; ++i) {
        Md q{A.a00 * p.a00 + A.a01 * p.a10,
             A.a00 * p.a01 + A.a01 * p.a11,
             A.a10 * p.a00 + A.a11 * p.a10,
             A.a10 * p.a01 + A.a11 * p.a11};
        p = q;
    }
    return p;
}
constexpr Md P64 = apow(64);

__global__ __launch_bounds__(256)
void holt_chunked_kernel(const float* __restrict__ x, float* __restrict__ out) {
    const int tid   = threadIdx.x;
    const int chunk = tid & (CHUNKS - 1);
    const int sloc  = tid >> 4;  // local sequence index, 0..15
    const int lane  = tid & 63;
    const int wv    = tid >> 6;
    const size_t seqBase = (size_t)blockIdx.x * SEQ_PER_BLOCK;
    const size_t base = (seqBase + sloc) * T_STEPS + (size_t)chunk * CLEN;

    // ---- Loads: per-thread strided float4 (R1 pattern). Keeps the ~50%
    // cross-iteration L3 input residency (FETCH ~137 GB) that Phase L lost.
    const float4* __restrict__ xv = reinterpret_cast<const float4*>(x + base);
    float4 v[CGROUPS];
#pragma unroll
    for (int g = 0; g < CGROUPS; ++g) v[g] = xv[g];

    float s = 0.0f, b = 0.0f;
    auto step = [&](float xval) {
        float sn = 0.5f * xval + 0.5f * (s + b);
        b = 0.5f * (sn - s) + 0.5f * b;
        s = sn;
    };

    // ---- Phase A: zero-init run, final state only ----
    if (chunk == 0) {
        // t=0: no update; t=1: no state update (quirky init); t=2,3: normal.
        step(v[0].z); step(v[0].w);
    } else {
        step(v[0].x); step(v[0].y); step(v[0].z); step(v[0].w);
    }
#pragma unroll
    for (int g = 1; g < CGROUPS; ++g) {
        step(v[g].x); step(v[g].y); step(v[g].z); step(v[g].w);
    }

    __shared__ float lS[256];
    __shared__ float lB[256];
    lS[tid] = s;
    lB[tid] = b;
    __syncthreads();

    // ---- Phase B: per-sequence scan over chunk states (16 threads active) ----
    if (tid < SEQ_PER_BLOCK) {
        const int o = tid * CHUNKS;
        const float p00 = (float)P64.a00, p01 = (float)P64.a01;
        const float p10 = (float)P64.a10, p11 = (float)P64.a11;
        float ts = lS[o], tb = lB[o];  // true state after chunk 0
        lS[o] = 0.0f; lB[o] = 0.0f;    // init for chunk 0
        for (int j = 1; j < CHUNKS; ++j) {
            float us = lS[o + j], ub = lB[o + j];
            lS[o + j] = ts;  lB[o + j] = tb;   // init state for chunk j
            float ns = us + p00 * ts + p01 * tb;
            float nb = ub + p10 * ts + p11 * tb;
            ts = ns; tb = nb;
        }
    }
    __syncthreads();

    // ---- Phase C: exact recurrence from corrected init; outputs -> v[] ----
    s = lS[sloc * CHUNKS + chunk];
    b = lB[sloc * CHUNKS + chunk];

    {
        float4 o0;
        if (chunk == 0) {
            o0.x = 0.0f;      // t=0
            o0.y = v[0].y;    // t=1 (state not updated)
            step(v[0].z); o0.z = s;
            step(v[0].w); o0.w = s;
        } else {
            step(v[0].x); o0.x = s;
            step(v[0].y); o0.y = s;
            step(v[0].z); o0.z = s;
            step(v[0].w); o0.w = s;
        }
        v[0] = o0;
    }
#pragma unroll
    for (int g = 1; g < CGROUPS; ++g) {
        float4 o;
        step(v[g].x); o.x = s;
        step(v[g].y); o.y = s;
        step(v[g].z); o.z = s;
        step(v[g].w); o.w = s;
        v[g] = o;
    }

    // ---- Phase D'': chunk-partitioned stages + fill-shaped stores ----
    // Stage k holds chunks 4k..4k+3 (all 16 gg) of all 16 sequences:
    //   16 seq x 4 chunk x 16 f4 = 1024 float4 = 16 KB.
    // Producer: only threads with chunk>>2 == k are active (16 lanes/wave);
    //   they write their 16 v[gg] at addr16 = sloc*64 + cloc*16 + (gg ^ f),
    //   f = (cloc<<1)|(sloc&1) -> 2 lanes per bank group (free, m136).
    // Consumer: wave wv, iter r: seqL = wv*4+r (uniform per instruction);
    //   lane l reads element (seqL, cloc=l>>4, gg=l&15) -- a permutation of
    //   64 consecutive f4 slots (uniform bank load) -- and stores to
    //   out_f4[(seqBase+seqL)*256 + k*64 + l]: 1 KiB contiguous lane-ordered,
    //   8 complete 128B lines per wave instruction (the fill kernel's shape).
    __shared__ float4 xfer[SEQ_PER_BLOCK * CHUNKS * 4];  // 1024 float4 = 16 KB

    const int cloc  = chunk & 3;
    const int kown  = chunk >> 2;
    const int fprod = (cloc << 1) | (sloc & 1);
    const int ccl   = lane >> 4;   // consumer chunk-within-stage
    const int cgg   = lane & 15;   // consumer f4-within-chunk
    float4* __restrict__ ov4 = reinterpret_cast<float4*>(out);

#pragma unroll
    for (int k = 0; k < 4; ++k) {
        if (kown == k) {
#pragma unroll
            for (int gg = 0; gg < CGROUPS; ++gg) {
                xfer[sloc * 64 + cloc * 16 + (gg ^ fprod)] = v[gg];
            }
        }
        __syncthreads();
#pragma unroll
        for (int r = 0; r < 4; ++r) {
            const int seqL = wv * 4 + r;
            const float4 val =
                xfer[seqL * 64 + ccl * 16 + (cgg ^ ((ccl << 1) | (seqL & 1)))];
            ov4[(seqBase + seqL) * (T_STEPS / 4) + k * 64 + lane] = val;
        }
        __syncthreads();
    }
}

extern "C" void kernel_launch(void* const* d_in, const int* in_sizes, int n_in,
                              void* d_out, int out_size, void* d_ws, size_t ws_size,
                              hipStream_t stream) {
    const float* x = (const float*)d_in[0];
    float* out = (float*)d_out;

    const int nseq = in_sizes[0] / T_STEPS;          // 65536
    const int grid = nseq / SEQ_PER_BLOCK;           // 4096 blocks

    holt_chunked_kernel<<<grid, 256, 0, stream>>>(x, out);
}